// Round 1
// baseline (1829.049 us; speedup 1.0000x reference)
//
#include <hip/hip_runtime.h>
#include <hip/hip_bf16.h>

#define B_ 2
#define C_ 256
#define H_ 64
#define W_ 64
#define N_ 4096  // H_*W_

typedef short bf16x8 __attribute__((ext_vector_type(8)));
typedef float f32x4 __attribute__((ext_vector_type(4)));

// float -> bf16 (round to nearest even), finite inputs
static __device__ __forceinline__ unsigned short f2bf(float f) {
    union { float f; unsigned u; } uf; uf.f = f;
    unsigned r = uf.u + 0x7fffu + ((uf.u >> 16) & 1u);
    return (unsigned short)(r >> 16);
}

// ---------------------------------------------------------------------------
// Direct 3x3 SAME conv + bias + relu, fp32 compute, bf16 output.
// Block: 256 threads. Each block: one (b, group of 4 c_out, quarter plane).
// TRANS=1: out layout [B][N][C] (position-major); TRANS=0: [B][C][N].
// ---------------------------------------------------------------------------
template<int TRANS>
__global__ __launch_bounds__(256) void conv3x3_relu_k(
    const float* __restrict__ x, const float* __restrict__ w,
    const float* __restrict__ bias, unsigned short* __restrict__ out)
{
    __shared__ float xs[18 * 64];
    __shared__ float wl[36];
    const int tid = threadIdx.x;
    const int bx  = blockIdx.x;           // 0..511
    const int b   = bx >> 8;
    const int rem = bx & 255;
    const int og  = rem >> 2;             // c_out group of 4: 0..63
    const int sq  = rem & 3;              // quarter plane: rows sq*16..+16
    const int row0 = sq << 4;

    float acc[4][4];
    #pragma unroll
    for (int o = 0; o < 4; ++o)
        #pragma unroll
        for (int j = 0; j < 4; ++j) acc[o][j] = 0.f;

    const int col = tid & 63;

    for (int ci = 0; ci < C_; ++ci) {
        const float* xp = x + (((size_t)b * C_ + ci) << 12);
        for (int idx = tid; idx < 18 * 64; idx += 256) {
            int r = idx >> 6, cc = idx & 63;
            int h = row0 - 1 + r;
            xs[idx] = (h >= 0 && h < 64) ? xp[(h << 6) + cc] : 0.f;
        }
        if (tid < 36) {
            int o_l = tid / 9, k = tid % 9;
            wl[tid] = w[(((size_t)(og * 4 + o_l)) * C_ + ci) * 9 + k];
        }
        __syncthreads();

        float wreg[36];
        #pragma unroll
        for (int i = 0; i < 36; ++i) wreg[i] = wl[i];

        #pragma unroll
        for (int j = 0; j < 4; ++j) {
            const int rl = (tid >> 6) + (j << 2);   // local output row 0..15
            #pragma unroll
            for (int dh = 0; dh < 3; ++dh) {
                const float* xr = &xs[(rl + dh) << 6];  // xs row (rl+dh) == h + dh - 1
                #pragma unroll
                for (int dw = 0; dw < 3; ++dw) {
                    int xc = col + dw - 1;
                    float v = (xc >= 0 && xc < 64) ? xr[xc] : 0.f;
                    #pragma unroll
                    for (int o = 0; o < 4; ++o)
                        acc[o][j] = fmaf(v, wreg[o * 9 + dh * 3 + dw], acc[o][j]);
                }
            }
        }
        __syncthreads();
    }

    #pragma unroll
    for (int o = 0; o < 4; ++o) {
        const int oc = og * 4 + o;
        const float bs = bias[oc];
        #pragma unroll
        for (int j = 0; j < 4; ++j) {
            int p_local = tid + (j << 8);
            int gp = (row0 << 6) + p_local;          // global position 0..4095
            float v = fmaxf(acc[o][j] + bs, 0.f);
            unsigned short bv = f2bf(v);
            if (TRANS) out[(((size_t)b * N_) + gp) * C_ + oc] = bv;
            else       out[(((size_t)b * C_) + oc) * N_ + gp] = bv;
        }
    }
}

// ---------------------------------------------------------------------------
// GEMM1: corrT[b][m][n] = sum_c f1x_t[b][m][c] * f1r_t[b][n][c]   (fp32 out)
// Both operands stored [N][C] bf16 -> identical fragment staging.
// Block 256 thr = 4 waves, 64x64 tile, K=256 in 8 steps of 32.
// ---------------------------------------------------------------------------
__global__ __launch_bounds__(256) void gemm_corr_k(
    const unsigned short* __restrict__ f1x, const unsigned short* __restrict__ f1r,
    float* __restrict__ corr)
{
    __shared__ alignas(16) unsigned short As[64][40];
    __shared__ alignas(16) unsigned short Bs[64][40];
    const int tid = threadIdx.x;
    const int tn = blockIdx.x;   // n tile
    const int tm = blockIdx.y;   // m tile
    const int b  = blockIdx.z;

    const unsigned short* Ab = f1x + ((size_t)b * N_ + (size_t)tm * 64) * C_;
    const unsigned short* Bb = f1r + ((size_t)b * N_ + (size_t)tn * 64) * C_;

    const int wid = tid >> 6, lane = tid & 63;
    const int wr = wid >> 1, wc = wid & 1;

    f32x4 acc[2][2];
    #pragma unroll
    for (int mi = 0; mi < 2; ++mi)
        #pragma unroll
        for (int ni = 0; ni < 2; ++ni)
            #pragma unroll
            for (int e = 0; e < 4; ++e) acc[mi][ni][e] = 0.f;

    const int r = tid >> 2, ch = tid & 3;
    const int row_a0 = wr * 32 + (lane & 15);
    const int row_b0 = wc * 32 + (lane & 15);
    const int ko = (lane >> 4) * 8;

    for (int k0 = 0; k0 < C_; k0 += 32) {
        *(float4*)&As[r][ch * 8] = *(const float4*)&Ab[(size_t)r * C_ + k0 + ch * 8];
        *(float4*)&Bs[r][ch * 8] = *(const float4*)&Bb[(size_t)r * C_ + k0 + ch * 8];
        __syncthreads();
        bf16x8 a0 = *(const bf16x8*)&As[row_a0][ko];
        bf16x8 a1 = *(const bf16x8*)&As[row_a0 + 16][ko];
        bf16x8 b0 = *(const bf16x8*)&Bs[row_b0][ko];
        bf16x8 b1 = *(const bf16x8*)&Bs[row_b0 + 16][ko];
        acc[0][0] = __builtin_amdgcn_mfma_f32_16x16x32_bf16(a0, b0, acc[0][0], 0, 0, 0);
        acc[0][1] = __builtin_amdgcn_mfma_f32_16x16x32_bf16(a0, b1, acc[0][1], 0, 0, 0);
        acc[1][0] = __builtin_amdgcn_mfma_f32_16x16x32_bf16(a1, b0, acc[1][0], 0, 0, 0);
        acc[1][1] = __builtin_amdgcn_mfma_f32_16x16x32_bf16(a1, b1, acc[1][1], 0, 0, 0);
        __syncthreads();
    }

    const int rbase = (lane >> 4) * 4;
    const int cbase = lane & 15;
    #pragma unroll
    for (int mi = 0; mi < 2; ++mi)
        #pragma unroll
        for (int ni = 0; ni < 2; ++ni)
            #pragma unroll
            for (int rr = 0; rr < 4; ++rr) {
                int m = tm * 64 + wr * 32 + mi * 16 + rbase + rr;
                int n = tn * 64 + wc * 32 + ni * 16 + cbase;
                corr[((size_t)b * N_ + m) * N_ + n] = acc[mi][ni][rr];
            }
}

// ---------------------------------------------------------------------------
// Row softmax in place over corrT rows (softmax over n for fixed m). fp32.
// One block per row; 256 threads x 16 elements.
// ---------------------------------------------------------------------------
__global__ __launch_bounds__(256) void softmax_rows_k(float* __restrict__ corr)
{
    __shared__ float red[4];
    const int m = blockIdx.x, b = blockIdx.y;
    float* row = corr + ((size_t)b * N_ + m) * N_;
    float4* row4 = (float4*)row;
    const int tid = threadIdx.x;
    const int wid = tid >> 6, lane = tid & 63;

    float4 v[4];
    float mx = -3.0e38f;
    #pragma unroll
    for (int j = 0; j < 4; ++j) {
        v[j] = row4[tid + j * 256];
        mx = fmaxf(mx, fmaxf(fmaxf(v[j].x, v[j].y), fmaxf(v[j].z, v[j].w)));
    }
    #pragma unroll
    for (int off = 32; off; off >>= 1) mx = fmaxf(mx, __shfl_xor(mx, off));
    if (lane == 0) red[wid] = mx;
    __syncthreads();
    mx = fmaxf(fmaxf(red[0], red[1]), fmaxf(red[2], red[3]));
    __syncthreads();

    float s = 0.f;
    #pragma unroll
    for (int j = 0; j < 4; ++j) {
        v[j].x = __expf(v[j].x - mx);
        v[j].y = __expf(v[j].y - mx);
        v[j].z = __expf(v[j].z - mx);
        v[j].w = __expf(v[j].w - mx);
        s += v[j].x + v[j].y + v[j].z + v[j].w;
    }
    #pragma unroll
    for (int off = 32; off; off >>= 1) s += __shfl_xor(s, off);
    if (lane == 0) red[wid] = s;
    __syncthreads();
    s = red[0] + red[1] + red[2] + red[3];
    const float inv = 1.f / s;
    #pragma unroll
    for (int j = 0; j < 4; ++j) {
        v[j].x *= inv; v[j].y *= inv; v[j].z *= inv; v[j].w *= inv;
        row4[tid + j * 256] = v[j];
    }
}

// ---------------------------------------------------------------------------
// GEMM2 + epilogue: out[b][c][m] = gamma * (sum_n f2[b][c][n] * P[n][m]) + x[b][c][m]
// P[n][m] = corrT[b][m][n] (softmaxed, fp32; cvt->bf16 during LDS staging).
// Block 64(c) x 64(m) tile, K=4096 in 128 steps of 32.
// ---------------------------------------------------------------------------
__global__ __launch_bounds__(256) void gemm_out_k(
    const unsigned short* __restrict__ f2, const float* __restrict__ corr,
    const float* __restrict__ x, const float* __restrict__ gamma,
    float* __restrict__ out)
{
    __shared__ alignas(16) unsigned short As[64][40];
    __shared__ alignas(16) unsigned short Bs[64][40];
    const int tid = threadIdx.x;
    const int tm = blockIdx.x;   // m tile 0..63
    const int tc = blockIdx.y;   // c tile 0..3
    const int b  = blockIdx.z;

    const unsigned short* Ab = f2 + ((size_t)b * C_ + (size_t)tc * 64) * N_;
    const float* Bb = corr + ((size_t)b * N_ + (size_t)tm * 64) * N_;

    const int wid = tid >> 6, lane = tid & 63;
    const int wr = wid >> 1, wc = wid & 1;

    f32x4 acc[2][2];
    #pragma unroll
    for (int mi = 0; mi < 2; ++mi)
        #pragma unroll
        for (int ni = 0; ni < 2; ++ni)
            #pragma unroll
            for (int e = 0; e < 4; ++e) acc[mi][ni][e] = 0.f;

    const int r = tid >> 2, ch = tid & 3;
    const int row_a0 = wr * 32 + (lane & 15);
    const int row_b0 = wc * 32 + (lane & 15);
    const int ko = (lane >> 4) * 8;

    for (int k0 = 0; k0 < N_; k0 += 32) {
        *(float4*)&As[r][ch * 8] = *(const float4*)&Ab[(size_t)r * N_ + k0 + ch * 8];
        {
            const float* src = &Bb[(size_t)r * N_ + k0 + ch * 8];
            float4 v0 = *(const float4*)&src[0];
            float4 v1 = *(const float4*)&src[4];
            union { unsigned short u[8]; float4 f; } pk;
            pk.u[0] = f2bf(v0.x); pk.u[1] = f2bf(v0.y);
            pk.u[2] = f2bf(v0.z); pk.u[3] = f2bf(v0.w);
            pk.u[4] = f2bf(v1.x); pk.u[5] = f2bf(v1.y);
            pk.u[6] = f2bf(v1.z); pk.u[7] = f2bf(v1.w);
            *(float4*)&Bs[r][ch * 8] = pk.f;
        }
        __syncthreads();
        bf16x8 a0 = *(const bf16x8*)&As[row_a0][ko];
        bf16x8 a1 = *(const bf16x8*)&As[row_a0 + 16][ko];
        bf16x8 b0 = *(const bf16x8*)&Bs[row_b0][ko];
        bf16x8 b1 = *(const bf16x8*)&Bs[row_b0 + 16][ko];
        acc[0][0] = __builtin_amdgcn_mfma_f32_16x16x32_bf16(a0, b0, acc[0][0], 0, 0, 0);
        acc[0][1] = __builtin_amdgcn_mfma_f32_16x16x32_bf16(a0, b1, acc[0][1], 0, 0, 0);
        acc[1][0] = __builtin_amdgcn_mfma_f32_16x16x32_bf16(a1, b0, acc[1][0], 0, 0, 0);
        acc[1][1] = __builtin_amdgcn_mfma_f32_16x16x32_bf16(a1, b1, acc[1][1], 0, 0, 0);
        __syncthreads();
    }

    const float g = gamma[0];
    const int rbase = (lane >> 4) * 4;
    const int cbase = lane & 15;
    #pragma unroll
    for (int mi = 0; mi < 2; ++mi)
        #pragma unroll
        for (int ni = 0; ni < 2; ++ni)
            #pragma unroll
            for (int rr = 0; rr < 4; ++rr) {
                int c = tc * 64 + wr * 32 + mi * 16 + rbase + rr;
                int m = tm * 64 + wc * 32 + ni * 16 + cbase;
                size_t oidx = ((size_t)b * C_ + c) * N_ + m;
                out[oidx] = acc[mi][ni][rr] * g + x[oidx];
            }
}

extern "C" void kernel_launch(void* const* d_in, const int* in_sizes, int n_in,
                              void* d_out, int out_size, void* d_ws, size_t ws_size,
                              hipStream_t stream) {
    const float* x     = (const float*)d_in[0];
    const float* ref_x = (const float*)d_in[1];
    const float* w1    = (const float*)d_in[2];
    const float* b1    = (const float*)d_in[3];
    const float* w2    = (const float*)d_in[4];
    const float* b2    = (const float*)d_in[5];
    const float* gamma = (const float*)d_in[6];
    float* out = (float*)d_out;

    char* ws = (char*)d_ws;
    size_t off = 0;
    auto nxt = [&](size_t bytes) {
        char* p = ws + off;
        off += (bytes + 255) & ~(size_t)255;
        return p;
    };
    unsigned short* f1x = (unsigned short*)nxt((size_t)B_ * N_ * C_ * 2);  // [b][m][c]
    unsigned short* f1r = (unsigned short*)nxt((size_t)B_ * N_ * C_ * 2);  // [b][n][c]
    unsigned short* f2  = (unsigned short*)nxt((size_t)B_ * N_ * C_ * 2);  // [b][c][n]
    float* corr = (float*)nxt((size_t)B_ * N_ * N_ * 4);                    // [b][m][n] = corr^T

    conv3x3_relu_k<1><<<512, 256, 0, stream>>>(x,     w1, b1, f1x);
    conv3x3_relu_k<1><<<512, 256, 0, stream>>>(ref_x, w1, b1, f1r);
    conv3x3_relu_k<0><<<512, 256, 0, stream>>>(x,     w2, b2, f2);
    gemm_corr_k<<<dim3(64, 64, B_), 256, 0, stream>>>(f1x, f1r, corr);
    softmax_rows_k<<<dim3(N_, B_), 256, 0, stream>>>(corr);
    gemm_out_k<<<dim3(64, 4, B_), 256, 0, stream>>>(f2, corr, x, gamma, out);
}

// Round 2
// 226.578 us; speedup vs baseline: 8.0725x; 8.0725x over previous
//
#include <hip/hip_runtime.h>
#include <hip/hip_bf16.h>

#define B_ 2
#define C_ 256
#define H_ 64
#define W_ 64
#define N_ 4096  // H_*W_

typedef short bf16x8 __attribute__((ext_vector_type(8)));
typedef _Float16 f16x8 __attribute__((ext_vector_type(8)));
typedef float f32x4 __attribute__((ext_vector_type(4)));

// float -> bf16 (round to nearest even), finite inputs
static __device__ __forceinline__ unsigned short f2bf(float f) {
    union { float f; unsigned u; } uf; uf.f = f;
    unsigned r = uf.u + 0x7fffu + ((uf.u >> 16) & 1u);
    return (unsigned short)(r >> 16);
}
// float -> fp16 bits
static __device__ __forceinline__ unsigned short f2h_u(float f) {
    union { _Float16 h; unsigned short u; } c; c.h = (_Float16)f; return c.u;
}

// ---------------------------------------------------------------------------
// Prep: [B][C][N] f32 -> [B][N][C] fp16 (transpose + convert), 64x64 tiles
// ---------------------------------------------------------------------------
__global__ __launch_bounds__(256) void cvt_x_k(const float* __restrict__ in,
                                               unsigned short* __restrict__ out)
{
    __shared__ unsigned short t[64][72];
    const int pt = blockIdx.x, ct = blockIdx.y, b = blockIdx.z;
    const int a = threadIdx.x & 63, r = threadIdx.x >> 6;
    #pragma unroll
    for (int i = 0; i < 16; ++i) {
        int c = i * 4 + r;
        t[c][a] = f2h_u(in[((size_t)(b * C_ + ct * 64 + c) << 12) + pt * 64 + a]);
    }
    __syncthreads();
    #pragma unroll
    for (int i = 0; i < 16; ++i) {
        int p = i * 4 + r;
        out[((size_t)(b * N_ + pt * 64 + p) << 8) + ct * 64 + a] = t[a][p];
    }
}

// Prep: w [O][I][3][3] f32 -> [tap][O][I] fp16
__global__ __launch_bounds__(256) void cvt_w_k(const float* __restrict__ w,
                                               unsigned short* __restrict__ wh)
{
    int i = blockIdx.x * 256 + threadIdx.x;         // < 9*256*256 exactly
    int ci = i & 255, co = (i >> 8) & 255, tap = i >> 16;
    wh[i] = f2h_u(w[((size_t)(co * 256 + ci)) * 9 + tap]);
}

// ---------------------------------------------------------------------------
// Implicit-GEMM 3x3 SAME conv + bias + relu via MFMA fp16.
// Block: 64 cout x 128 pos (2 plane rows). 4 waves (2co x 2pos), wave 32x64.
// K = 256 ci in steps of 32; 9 taps per step from a haloed LDS window.
// XOR chunk swizzle keeps ds_read_b128 at 2 lanes/bank (free).
// TRANS=1: out [B][N][C] bf16; TRANS=0: out [B][C][N] bf16.
// ---------------------------------------------------------------------------
template<int TRANS>
__global__ __launch_bounds__(256) void conv_mfma_k(
    const unsigned short* __restrict__ xt,   // [b][4096][256] fp16
    const unsigned short* __restrict__ wt,   // [9][256][256]  fp16
    const float* __restrict__ bias,
    unsigned short* __restrict__ out)
{
    __shared__ unsigned short As[9 * 64 * 32];   // [tap][co][ci-chunk swz]
    __shared__ unsigned short Bs[4 * 66 * 32];   // [row][col(pad)][ci-chunk swz]
    const int tid = threadIdx.x;
    const int pt  = blockIdx.x;   // 0..31 : plane rows pt*2, pt*2+1
    const int cot = blockIdx.y;   // 0..3
    const int b   = blockIdx.z;

    const int lane = tid & 63, wid = tid >> 6;
    const int wco = wid >> 1, wpos = wid & 1;
    const int rl = lane & 15, q = lane >> 4;
    const int r0 = pt * 2;

    f32x4 acc[2][4];
    #pragma unroll
    for (int mi = 0; mi < 2; ++mi)
        #pragma unroll
        for (int ni = 0; ni < 4; ++ni)
            #pragma unroll
            for (int e = 0; e < 4; ++e) acc[mi][ni][e] = 0.f;

    for (int k0 = 0; k0 < C_; k0 += 32) {
        // stage A: 9*64*4 = 2304 16B-chunks
        #pragma unroll
        for (int j = 0; j < 9; ++j) {
            int it = tid + j * 256;
            int tap = it >> 8, co = (it >> 2) & 63, qa = it & 3;
            const unsigned short* src =
                wt + ((size_t)(tap * C_ + cot * 64 + co) << 8) + k0 + qa * 8;
            int chunk = qa ^ ((co >> 1) & 3);
            *(float4*)&As[(tap * 64 + co) * 32 + chunk * 8] = *(const float4*)src;
        }
        // stage B: 4*66*4 = 1056 16B-chunks (zero-padded halo)
        #pragma unroll
        for (int j = 0; j < 5; ++j) {
            int it = tid + j * 256;
            if (it < 1056) {
                int row = it / 264;
                int rem = it - row * 264;
                int col = rem >> 2, qb = rem & 3;
                int h = r0 + row - 1, c = col - 1;
                float4 v; v.x = 0.f; v.y = 0.f; v.z = 0.f; v.w = 0.f;
                if (h >= 0 && h < 64 && c >= 0 && c < 64)
                    v = *(const float4*)(xt + ((size_t)(b * N_ + h * 64 + c) << 8) + k0 + qb * 8);
                int chunk = qb ^ ((col >> 1) & 3);
                *(float4*)&Bs[(row * 66 + col) * 32 + chunk * 8] = v;
            }
        }
        __syncthreads();

        const int chunkA = q ^ ((rl >> 1) & 3);
        #pragma unroll
        for (int tap = 0; tap < 9; ++tap) {
            const int kh = tap / 3, kw = tap % 3;
            f16x8 a0 = *(const f16x8*)&As[((tap * 64) + wco * 32 + rl) * 32 + chunkA * 8];
            f16x8 a1 = *(const f16x8*)&As[((tap * 64) + wco * 32 + 16 + rl) * 32 + chunkA * 8];
            const int chunkB = q ^ (((rl + kw) >> 1) & 3);
            const int rowB = (wpos + kh) * 66;
            #pragma unroll
            for (int ni = 0; ni < 4; ++ni) {
                int colB = ni * 16 + rl + kw;
                f16x8 bf = *(const f16x8*)&Bs[(rowB + colB) * 32 + chunkB * 8];
                acc[0][ni] = __builtin_amdgcn_mfma_f32_16x16x32_f16(a0, bf, acc[0][ni], 0, 0, 0);
                acc[1][ni] = __builtin_amdgcn_mfma_f32_16x16x32_f16(a1, bf, acc[1][ni], 0, 0, 0);
            }
        }
        __syncthreads();
    }

    // epilogue: C/D layout col=lane&15, row=(lane>>4)*4+rr
    #pragma unroll
    for (int mi = 0; mi < 2; ++mi) {
        const int co = cot * 64 + wco * 32 + mi * 16 + q * 4;
        float bs[4];
        #pragma unroll
        for (int rr = 0; rr < 4; ++rr) bs[rr] = bias[co + rr];
        #pragma unroll
        for (int ni = 0; ni < 4; ++ni) {
            const int pos = pt * 128 + wpos * 64 + ni * 16 + rl;
            if (TRANS) {
                unsigned short pk[4];
                #pragma unroll
                for (int rr = 0; rr < 4; ++rr)
                    pk[rr] = f2bf(fmaxf(acc[mi][ni][rr] + bs[rr], 0.f));
                uint2 u;
                u.x = (unsigned)pk[0] | ((unsigned)pk[1] << 16);
                u.y = (unsigned)pk[2] | ((unsigned)pk[3] << 16);
                *(uint2*)&out[((size_t)(b * N_ + pos) << 8) + co] = u;
            } else {
                #pragma unroll
                for (int rr = 0; rr < 4; ++rr)
                    out[((size_t)(b * C_ + co + rr) << 12) + pos] =
                        f2bf(fmaxf(acc[mi][ni][rr] + bs[rr], 0.f));
            }
        }
    }
}

// ---------------------------------------------------------------------------
// GEMM1: corrT[b][m][n] = sum_c f1x[b][m][c] * f1r[b][n][c]   (fp32 out)
// ---------------------------------------------------------------------------
__global__ __launch_bounds__(256) void gemm_corr_k(
    const unsigned short* __restrict__ f1x, const unsigned short* __restrict__ f1r,
    float* __restrict__ corr)
{
    __shared__ alignas(16) unsigned short As[64][40];
    __shared__ alignas(16) unsigned short Bs[64][40];
    const int tid = threadIdx.x;
    const int tn = blockIdx.x;
    const int tm = blockIdx.y;
    const int b  = blockIdx.z;

    const unsigned short* Ab = f1x + ((size_t)b * N_ + (size_t)tm * 64) * C_;
    const unsigned short* Bb = f1r + ((size_t)b * N_ + (size_t)tn * 64) * C_;

    const int wid = tid >> 6, lane = tid & 63;
    const int wr = wid >> 1, wc = wid & 1;

    f32x4 acc[2][2];
    #pragma unroll
    for (int mi = 0; mi < 2; ++mi)
        #pragma unroll
        for (int ni = 0; ni < 2; ++ni)
            #pragma unroll
            for (int e = 0; e < 4; ++e) acc[mi][ni][e] = 0.f;

    const int r = tid >> 2, ch = tid & 3;
    const int row_a0 = wr * 32 + (lane & 15);
    const int row_b0 = wc * 32 + (lane & 15);
    const int ko = (lane >> 4) * 8;

    for (int k0 = 0; k0 < C_; k0 += 32) {
        *(float4*)&As[r][ch * 8] = *(const float4*)&Ab[(size_t)r * C_ + k0 + ch * 8];
        *(float4*)&Bs[r][ch * 8] = *(const float4*)&Bb[(size_t)r * C_ + k0 + ch * 8];
        __syncthreads();
        bf16x8 a0 = *(const bf16x8*)&As[row_a0][ko];
        bf16x8 a1 = *(const bf16x8*)&As[row_a0 + 16][ko];
        bf16x8 b0 = *(const bf16x8*)&Bs[row_b0][ko];
        bf16x8 b1 = *(const bf16x8*)&Bs[row_b0 + 16][ko];
        acc[0][0] = __builtin_amdgcn_mfma_f32_16x16x32_bf16(a0, b0, acc[0][0], 0, 0, 0);
        acc[0][1] = __builtin_amdgcn_mfma_f32_16x16x32_bf16(a0, b1, acc[0][1], 0, 0, 0);
        acc[1][0] = __builtin_amdgcn_mfma_f32_16x16x32_bf16(a1, b0, acc[1][0], 0, 0, 0);
        acc[1][1] = __builtin_amdgcn_mfma_f32_16x16x32_bf16(a1, b1, acc[1][1], 0, 0, 0);
        __syncthreads();
    }

    const int rbase = (lane >> 4) * 4;
    const int cbase = lane & 15;
    #pragma unroll
    for (int mi = 0; mi < 2; ++mi)
        #pragma unroll
        for (int ni = 0; ni < 2; ++ni)
            #pragma unroll
            for (int rr = 0; rr < 4; ++rr) {
                int m = tm * 64 + wr * 32 + mi * 16 + rbase + rr;
                int n = tn * 64 + wc * 32 + ni * 16 + cbase;
                corr[((size_t)b * N_ + m) * N_ + n] = acc[mi][ni][rr];
            }
}

// ---------------------------------------------------------------------------
// Row softmax over corrT rows; reads fp32, writes bf16 packed into the
// FRONT half of the same row (in-place, block owns its row).
// ---------------------------------------------------------------------------
__global__ __launch_bounds__(256) void softmax_rows_k(float* __restrict__ corr)
{
    __shared__ float red[4];
    const int m = blockIdx.x, b = blockIdx.y;
    float* row = corr + ((size_t)b * N_ + m) * N_;
    float4* row4 = (float4*)row;
    const int tid = threadIdx.x;
    const int wid = tid >> 6, lane = tid & 63;

    float4 v[4];
    float mx = -3.0e38f;
    #pragma unroll
    for (int j = 0; j < 4; ++j) {
        v[j] = row4[tid + j * 256];
        mx = fmaxf(mx, fmaxf(fmaxf(v[j].x, v[j].y), fmaxf(v[j].z, v[j].w)));
    }
    #pragma unroll
    for (int off = 32; off; off >>= 1) mx = fmaxf(mx, __shfl_xor(mx, off));
    if (lane == 0) red[wid] = mx;
    __syncthreads();
    mx = fmaxf(fmaxf(red[0], red[1]), fmaxf(red[2], red[3]));
    __syncthreads();

    float s = 0.f;
    #pragma unroll
    for (int j = 0; j < 4; ++j) {
        v[j].x = __expf(v[j].x - mx);
        v[j].y = __expf(v[j].y - mx);
        v[j].z = __expf(v[j].z - mx);
        v[j].w = __expf(v[j].w - mx);
        s += v[j].x + v[j].y + v[j].z + v[j].w;
    }
    #pragma unroll
    for (int off = 32; off; off >>= 1) s += __shfl_xor(s, off);
    if (lane == 0) red[wid] = s;
    __syncthreads();
    s = red[0] + red[1] + red[2] + red[3];
    const float inv = 1.f / s;

    unsigned short* rb = (unsigned short*)row;
    #pragma unroll
    for (int j = 0; j < 4; ++j) {
        uint2 u;
        u.x = (unsigned)f2bf(v[j].x * inv) | ((unsigned)f2bf(v[j].y * inv) << 16);
        u.y = (unsigned)f2bf(v[j].z * inv) | ((unsigned)f2bf(v[j].w * inv) << 16);
        *(uint2*)&rb[4 * (tid + j * 256)] = u;
    }
}

// ---------------------------------------------------------------------------
// GEMM2 + epilogue: out[b][c][m] = gamma * sum_n f2[b][c][n]*P[n][m] + x[b][c][m]
// P read as bf16 rows packed at stride 8192 ushorts (front half of fp32 rows).
// ---------------------------------------------------------------------------
__global__ __launch_bounds__(256) void gemm_out_k(
    const unsigned short* __restrict__ f2, const float* __restrict__ corr,
    const float* __restrict__ x, const float* __restrict__ gamma,
    float* __restrict__ out)
{
    __shared__ alignas(16) unsigned short As[64][40];
    __shared__ alignas(16) unsigned short Bs[64][40];
    const int tid = threadIdx.x;
    const int tm = blockIdx.x;
    const int tc = blockIdx.y;
    const int b  = blockIdx.z;

    const unsigned short* Ab = f2 + ((size_t)b * C_ + (size_t)tc * 64) * N_;
    const unsigned short* Bb = (const unsigned short*)corr
                             + ((size_t)b * N_ + (size_t)tm * 64) * 8192;

    const int wid = tid >> 6, lane = tid & 63;
    const int wr = wid >> 1, wc = wid & 1;

    f32x4 acc[2][2];
    #pragma unroll
    for (int mi = 0; mi < 2; ++mi)
        #pragma unroll
        for (int ni = 0; ni < 2; ++ni)
            #pragma unroll
            for (int e = 0; e < 4; ++e) acc[mi][ni][e] = 0.f;

    const int r = tid >> 2, ch = tid & 3;
    const int row_a0 = wr * 32 + (lane & 15);
    const int row_b0 = wc * 32 + (lane & 15);
    const int ko = (lane >> 4) * 8;

    for (int k0 = 0; k0 < N_; k0 += 32) {
        *(float4*)&As[r][ch * 8] = *(const float4*)&Ab[(size_t)r * N_ + k0 + ch * 8];
        *(float4*)&Bs[r][ch * 8] = *(const float4*)&Bb[(size_t)r * 8192 + k0 + ch * 8];
        __syncthreads();
        bf16x8 a0 = *(const bf16x8*)&As[row_a0][ko];
        bf16x8 a1 = *(const bf16x8*)&As[row_a0 + 16][ko];
        bf16x8 b0 = *(const bf16x8*)&Bs[row_b0][ko];
        bf16x8 b1 = *(const bf16x8*)&Bs[row_b0 + 16][ko];
        acc[0][0] = __builtin_amdgcn_mfma_f32_16x16x32_bf16(a0, b0, acc[0][0], 0, 0, 0);
        acc[0][1] = __builtin_amdgcn_mfma_f32_16x16x32_bf16(a0, b1, acc[0][1], 0, 0, 0);
        acc[1][0] = __builtin_amdgcn_mfma_f32_16x16x32_bf16(a1, b0, acc[1][0], 0, 0, 0);
        acc[1][1] = __builtin_amdgcn_mfma_f32_16x16x32_bf16(a1, b1, acc[1][1], 0, 0, 0);
        __syncthreads();
    }

    const float g = gamma[0];
    const int rbase = (lane >> 4) * 4;
    const int cbase = lane & 15;
    #pragma unroll
    for (int mi = 0; mi < 2; ++mi)
        #pragma unroll
        for (int ni = 0; ni < 2; ++ni)
            #pragma unroll
            for (int rr = 0; rr < 4; ++rr) {
                int c = tc * 64 + wr * 32 + mi * 16 + rbase + rr;
                int m = tm * 64 + wc * 32 + ni * 16 + cbase;
                size_t oidx = ((size_t)b * C_ + c) * N_ + m;
                out[oidx] = acc[mi][ni][rr] * g + x[oidx];
            }
}

extern "C" void kernel_launch(void* const* d_in, const int* in_sizes, int n_in,
                              void* d_out, int out_size, void* d_ws, size_t ws_size,
                              hipStream_t stream) {
    const float* x     = (const float*)d_in[0];
    const float* ref_x = (const float*)d_in[1];
    const float* w1    = (const float*)d_in[2];
    const float* b1    = (const float*)d_in[3];
    const float* w2    = (const float*)d_in[4];
    const float* b2    = (const float*)d_in[5];
    const float* gamma = (const float*)d_in[6];
    float* out = (float*)d_out;

    char* ws = (char*)d_ws;
    size_t off = 0;
    auto nxt = [&](size_t bytes) {
        char* p = ws + off;
        off += (bytes + 255) & ~(size_t)255;
        return p;
    };
    unsigned short* f1x = (unsigned short*)nxt((size_t)B_ * N_ * C_ * 2);  // bf16 [b][m][c]
    unsigned short* f1r = (unsigned short*)nxt((size_t)B_ * N_ * C_ * 2);  // bf16 [b][n][c]
    unsigned short* f2  = (unsigned short*)nxt((size_t)B_ * N_ * C_ * 2);  // bf16 [b][c][n]
    unsigned short* xtx = (unsigned short*)nxt((size_t)B_ * N_ * C_ * 2);  // fp16 [b][p][c]
    unsigned short* xtr = (unsigned short*)nxt((size_t)B_ * N_ * C_ * 2);  // fp16 [b][p][c]
    unsigned short* w1h = (unsigned short*)nxt((size_t)9 * C_ * C_ * 2);   // fp16 [tap][o][i]
    unsigned short* w2h = (unsigned short*)nxt((size_t)9 * C_ * C_ * 2);   // fp16 [tap][o][i]
    float* corr = (float*)nxt((size_t)B_ * N_ * N_ * 4);                   // fp32 corrT [b][m][n]

    cvt_x_k<<<dim3(64, 4, B_), 256, 0, stream>>>(x, xtx);
    cvt_x_k<<<dim3(64, 4, B_), 256, 0, stream>>>(ref_x, xtr);
    cvt_w_k<<<2304, 256, 0, stream>>>(w1, w1h);
    cvt_w_k<<<2304, 256, 0, stream>>>(w2, w2h);

    conv_mfma_k<1><<<dim3(32, 4, B_), 256, 0, stream>>>(xtx, w1h, b1, f1x);
    conv_mfma_k<1><<<dim3(32, 4, B_), 256, 0, stream>>>(xtr, w1h, b1, f1r);
    conv_mfma_k<0><<<dim3(32, 4, B_), 256, 0, stream>>>(xtx, w2h, b2, f2);

    gemm_corr_k<<<dim3(64, 64, B_), 256, 0, stream>>>(f1x, f1r, corr);
    softmax_rows_k<<<dim3(N_, B_), 256, 0, stream>>>(corr);
    gemm_out_k<<<dim3(64, 4, B_), 256, 0, stream>>>(f2, corr, x, gamma, out);
}

// Round 3
// 218.181 us; speedup vs baseline: 8.3832x; 1.0385x over previous
//
#include <hip/hip_runtime.h>
#include <hip/hip_bf16.h>

#define B_ 2
#define C_ 256
#define H_ 64
#define W_ 64
#define N_ 4096  // H_*W_

typedef short bf16x8 __attribute__((ext_vector_type(8)));
typedef _Float16 f16x8 __attribute__((ext_vector_type(8)));
typedef float f32x4 __attribute__((ext_vector_type(4)));

// float -> bf16 (round to nearest even), finite inputs
static __device__ __forceinline__ unsigned short f2bf(float f) {
    union { float f; unsigned u; } uf; uf.f = f;
    unsigned r = uf.u + 0x7fffu + ((uf.u >> 16) & 1u);
    return (unsigned short)(r >> 16);
}
// float -> fp16 bits
static __device__ __forceinline__ unsigned short f2h_u(float f) {
    union { _Float16 h; unsigned short u; } c; c.h = (_Float16)f; return c.u;
}

// async global->LDS, 16B per lane. LDS dest must be wave-uniform base + lane*16.
static __device__ __forceinline__ void gload16(const void* g, void* l) {
    __builtin_amdgcn_global_load_lds(
        (const __attribute__((address_space(1))) unsigned int*)g,
        (__attribute__((address_space(3))) unsigned int*)l, 16, 0, 0);
}

// ---------------------------------------------------------------------------
// Prep: [B][C][N] f32 -> [B][N][C] fp16 (transpose + convert), 64x64 tiles
// ---------------------------------------------------------------------------
__global__ __launch_bounds__(256) void cvt_x_k(const float* __restrict__ in,
                                               unsigned short* __restrict__ out)
{
    __shared__ unsigned short t[64][72];
    const int pt = blockIdx.x, ct = blockIdx.y, b = blockIdx.z;
    const int a = threadIdx.x & 63, r = threadIdx.x >> 6;
    #pragma unroll
    for (int i = 0; i < 16; ++i) {
        int c = i * 4 + r;
        t[c][a] = f2h_u(in[((size_t)(b * C_ + ct * 64 + c) << 12) + pt * 64 + a]);
    }
    __syncthreads();
    #pragma unroll
    for (int i = 0; i < 16; ++i) {
        int p = i * 4 + r;
        out[((size_t)(b * N_ + pt * 64 + p) << 8) + ct * 64 + a] = t[a][p];
    }
}

// Prep: w [O][I][3][3] f32 -> [tap][O][I] fp16
__global__ __launch_bounds__(256) void cvt_w_k(const float* __restrict__ w,
                                               unsigned short* __restrict__ wh)
{
    int i = blockIdx.x * 256 + threadIdx.x;         // < 9*256*256 exactly
    int ci = i & 255, co = (i >> 8) & 255, tap = i >> 16;
    wh[i] = f2h_u(w[((size_t)(co * 256 + ci)) * 9 + tap]);
}

// ---------------------------------------------------------------------------
// Implicit-GEMM 3x3 SAME conv + bias + relu via MFMA fp16.
// Block: 64 cout x 128 pos (2 plane rows). 4 waves (2co x 2pos).
// Weights staged via global_load_lds into chunk-major LDS [q][tap*64+co]
// (frag reads then hit 2 lanes/bank = free). X window reg-staged w/ halo+swz.
// ---------------------------------------------------------------------------
template<int TRANS>
__global__ __launch_bounds__(256) void conv_mfma_k(
    const unsigned short* __restrict__ xt,   // [b][4096][256] fp16
    const unsigned short* __restrict__ wt,   // [9][256][256]  fp16
    const float* __restrict__ bias,
    unsigned short* __restrict__ out)
{
    __shared__ unsigned short As[4 * 576 * 8];   // (q*576 + tap*64 + co)*8
    __shared__ unsigned short Bs[4 * 66 * 32];   // [row][col(pad)][ci-chunk swz]
    const int tid = threadIdx.x;
    const int pt  = blockIdx.x;   // 0..31 : plane rows pt*2, pt*2+1
    const int cot = blockIdx.y;   // 0..3
    const int b   = blockIdx.z;

    const int lane = tid & 63, wid = tid >> 6;
    const int wco = wid >> 1, wpos = wid & 1;
    const int rl = lane & 15, q = lane >> 4;
    const int r0 = pt * 2;

    f32x4 acc[2][4];
    #pragma unroll
    for (int mi = 0; mi < 2; ++mi)
        #pragma unroll
        for (int ni = 0; ni < 4; ++ni)
            #pragma unroll
            for (int e = 0; e < 4; ++e) acc[mi][ni][e] = 0.f;

    for (int k0 = 0; k0 < C_; k0 += 32) {
        // stage A via global_load_lds: wave `wid` stages k-chunk q=wid, all taps
        #pragma unroll
        for (int tap = 0; tap < 9; ++tap) {
            gload16(wt + ((size_t)(tap * C_ + cot * 64 + lane) << 8) + k0 + wid * 8,
                    &As[(wid * 576 + tap * 64 + lane) * 8]);
        }
        // stage B: 4*66*4 = 1056 16B-chunks (zero-padded halo), swizzled
        #pragma unroll
        for (int j = 0; j < 5; ++j) {
            int it = tid + j * 256;
            if (it < 1056) {
                int col = it >> 4, sub = it & 15;
                int row = sub >> 2, qb = sub & 3;
                int h = r0 + row - 1, c = col - 1;
                float4 v; v.x = 0.f; v.y = 0.f; v.z = 0.f; v.w = 0.f;
                if (h >= 0 && h < 64 && c >= 0 && c < 64)
                    v = *(const float4*)(xt + ((size_t)(b * N_ + h * 64 + c) << 8) + k0 + qb * 8);
                int chunk = qb ^ ((col >> 1) & 3);
                *(float4*)&Bs[(row * 66 + col) * 32 + chunk * 8] = v;
            }
        }
        __syncthreads();

        #pragma unroll
        for (int tap = 0; tap < 9; ++tap) {
            const int kh = tap / 3, kw = tap % 3;
            f16x8 a0 = *(const f16x8*)&As[(q * 576 + tap * 64 + wco * 32 + rl) * 8];
            f16x8 a1 = *(const f16x8*)&As[(q * 576 + tap * 64 + wco * 32 + 16 + rl) * 8];
            const int chunkB = q ^ (((rl + kw) >> 1) & 3);
            const int rowB = (wpos + kh) * 66;
            #pragma unroll
            for (int ni = 0; ni < 4; ++ni) {
                int colB = ni * 16 + rl + kw;
                f16x8 bf = *(const f16x8*)&Bs[(rowB + colB) * 32 + chunkB * 8];
                acc[0][ni] = __builtin_amdgcn_mfma_f32_16x16x32_f16(a0, bf, acc[0][ni], 0, 0, 0);
                acc[1][ni] = __builtin_amdgcn_mfma_f32_16x16x32_f16(a1, bf, acc[1][ni], 0, 0, 0);
            }
        }
        __syncthreads();
    }

    // epilogue: C/D layout col=lane&15, row=(lane>>4)*4+rr
    #pragma unroll
    for (int mi = 0; mi < 2; ++mi) {
        const int co = cot * 64 + wco * 32 + mi * 16 + q * 4;
        float bs[4];
        #pragma unroll
        for (int rr = 0; rr < 4; ++rr) bs[rr] = bias[co + rr];
        #pragma unroll
        for (int ni = 0; ni < 4; ++ni) {
            const int pos = pt * 128 + wpos * 64 + ni * 16 + rl;
            if (TRANS) {
                unsigned short pk[4];
                #pragma unroll
                for (int rr = 0; rr < 4; ++rr)
                    pk[rr] = f2bf(fmaxf(acc[mi][ni][rr] + bs[rr], 0.f));
                uint2 u;
                u.x = (unsigned)pk[0] | ((unsigned)pk[1] << 16);
                u.y = (unsigned)pk[2] | ((unsigned)pk[3] << 16);
                *(uint2*)&out[((size_t)(b * N_ + pos) << 8) + co] = u;
            } else {
                #pragma unroll
                for (int rr = 0; rr < 4; ++rr)
                    out[((size_t)(b * C_ + co + rr) << 12) + pos] =
                        f2bf(fmaxf(acc[mi][ni][rr] + bs[rr], 0.f));
            }
        }
    }
}

// ---------------------------------------------------------------------------
// GEMM1 (m97 structure): corrT[b][m][n] = sum_c f1x[b][m][c]*f1r[b][n][c]
// 128x128 tile, 4 waves (2x2, each 64x64 = 4x4 frags), global_load_lds.
// ---------------------------------------------------------------------------
__global__ __launch_bounds__(256) void gemm_corr_k(
    const unsigned short* __restrict__ f1x, const unsigned short* __restrict__ f1r,
    float* __restrict__ corr)
{
    __shared__ alignas(16) unsigned short As[128 * 32];
    __shared__ alignas(16) unsigned short Bs[128 * 32];
    const int tid = threadIdx.x;
    const int tn = blockIdx.x, tm = blockIdx.y, b = blockIdx.z;

    const unsigned short* Ab = f1x + ((size_t)b * N_ + (size_t)tm * 128) * C_;
    const unsigned short* Bb = f1r + ((size_t)b * N_ + (size_t)tn * 128) * C_;

    const int wid = tid >> 6, lane = tid & 63;
    const int wr = wid >> 1, wc = wid & 1;
    const int rl = lane & 15, q = lane >> 4;
    const int srow = wid * 32 + (lane >> 2), sq = lane & 3;

    f32x4 acc[4][4];
    #pragma unroll
    for (int mi = 0; mi < 4; ++mi)
        #pragma unroll
        for (int ni = 0; ni < 4; ++ni)
            #pragma unroll
            for (int e = 0; e < 4; ++e) acc[mi][ni][e] = 0.f;

    for (int k0 = 0; k0 < C_; k0 += 32) {
        gload16(&Ab[(size_t)srow * C_ + k0 + sq * 8],        &As[srow * 32 + sq * 8]);
        gload16(&Ab[(size_t)(srow + 16) * C_ + k0 + sq * 8], &As[(srow + 16) * 32 + sq * 8]);
        gload16(&Bb[(size_t)srow * C_ + k0 + sq * 8],        &Bs[srow * 32 + sq * 8]);
        gload16(&Bb[(size_t)(srow + 16) * C_ + k0 + sq * 8], &Bs[(srow + 16) * 32 + sq * 8]);
        __syncthreads();
        bf16x8 a[4], bb[4];
        #pragma unroll
        for (int mi = 0; mi < 4; ++mi)
            a[mi] = *(const bf16x8*)&As[(wr * 64 + mi * 16 + rl) * 32 + q * 8];
        #pragma unroll
        for (int ni = 0; ni < 4; ++ni)
            bb[ni] = *(const bf16x8*)&Bs[(wc * 64 + ni * 16 + rl) * 32 + q * 8];
        #pragma unroll
        for (int mi = 0; mi < 4; ++mi)
            #pragma unroll
            for (int ni = 0; ni < 4; ++ni)
                acc[mi][ni] = __builtin_amdgcn_mfma_f32_16x16x32_bf16(a[mi], bb[ni], acc[mi][ni], 0, 0, 0);
        __syncthreads();
    }

    #pragma unroll
    for (int mi = 0; mi < 4; ++mi)
        #pragma unroll
        for (int ni = 0; ni < 4; ++ni)
            #pragma unroll
            for (int rr = 0; rr < 4; ++rr) {
                int m = tm * 128 + wr * 64 + mi * 16 + q * 4 + rr;
                int n = tn * 128 + wc * 64 + ni * 16 + rl;
                corr[((size_t)b * N_ + m) * N_ + n] = acc[mi][ni][rr];
            }
}

// ---------------------------------------------------------------------------
// Row softmax over corrT rows; reads fp32, writes bf16 packed into the
// FRONT half of the same row (in-place, block owns its row).
// ---------------------------------------------------------------------------
__global__ __launch_bounds__(256) void softmax_rows_k(float* __restrict__ corr)
{
    __shared__ float red[4];
    const int m = blockIdx.x, b = blockIdx.y;
    float* row = corr + ((size_t)b * N_ + m) * N_;
    float4* row4 = (float4*)row;
    const int tid = threadIdx.x;
    const int wid = tid >> 6, lane = tid & 63;

    float4 v[4];
    float mx = -3.0e38f;
    #pragma unroll
    for (int j = 0; j < 4; ++j) {
        v[j] = row4[tid + j * 256];
        mx = fmaxf(mx, fmaxf(fmaxf(v[j].x, v[j].y), fmaxf(v[j].z, v[j].w)));
    }
    #pragma unroll
    for (int off = 32; off; off >>= 1) mx = fmaxf(mx, __shfl_xor(mx, off));
    if (lane == 0) red[wid] = mx;
    __syncthreads();
    mx = fmaxf(fmaxf(red[0], red[1]), fmaxf(red[2], red[3]));
    __syncthreads();

    float s = 0.f;
    #pragma unroll
    for (int j = 0; j < 4; ++j) {
        v[j].x = __expf(v[j].x - mx);
        v[j].y = __expf(v[j].y - mx);
        v[j].z = __expf(v[j].z - mx);
        v[j].w = __expf(v[j].w - mx);
        s += v[j].x + v[j].y + v[j].z + v[j].w;
    }
    #pragma unroll
    for (int off = 32; off; off >>= 1) s += __shfl_xor(s, off);
    if (lane == 0) red[wid] = s;
    __syncthreads();
    s = red[0] + red[1] + red[2] + red[3];
    const float inv = 1.f / s;

    unsigned short* rb = (unsigned short*)row;
    #pragma unroll
    for (int j = 0; j < 4; ++j) {
        uint2 u;
        u.x = (unsigned)f2bf(v[j].x * inv) | ((unsigned)f2bf(v[j].y * inv) << 16);
        u.y = (unsigned)f2bf(v[j].z * inv) | ((unsigned)f2bf(v[j].w * inv) << 16);
        *(uint2*)&rb[4 * (tid + j * 256)] = u;
    }
}

// ---------------------------------------------------------------------------
// GEMM2 split-K: part[b][c][m] = sum_{n in split} f2[b][c][n] * P[m][n]
// Tile 128c x 128m, 8 waves (2c x 4m, each 64x32 = 4x2 frags), split-K=2.
// P read as bf16 rows packed at stride 8192 ushorts.
// ---------------------------------------------------------------------------
__global__ __launch_bounds__(512) void gemm_out_k(
    const unsigned short* __restrict__ f2, const float* __restrict__ corr,
    float* __restrict__ p0, float* __restrict__ p1)
{
    __shared__ alignas(16) unsigned short As[128 * 32];
    __shared__ alignas(16) unsigned short Bs[128 * 32];
    const int tid = threadIdx.x;
    const int tm = blockIdx.x;                 // 0..31
    const int tc = blockIdx.y >> 1;            // 0..1
    const int s  = blockIdx.y & 1;             // split 0..1
    const int b  = blockIdx.z;

    const unsigned short* Ab = f2 + ((size_t)b * C_ + (size_t)tc * 128) * N_;
    const unsigned short* Bb = (const unsigned short*)corr
                             + ((size_t)b * N_ + (size_t)tm * 128) * 8192;

    const int wid = tid >> 6, lane = tid & 63;
    const int wc = wid >> 2, wm = wid & 3;
    const int rl = lane & 15, q = lane >> 4;
    const int srow = wid * 16 + (lane >> 2), sq = lane & 3;
    const int nbase = s * 2048;

    f32x4 acc[4][2];
    #pragma unroll
    for (int mi = 0; mi < 4; ++mi)
        #pragma unroll
        for (int ni = 0; ni < 2; ++ni)
            #pragma unroll
            for (int e = 0; e < 4; ++e) acc[mi][ni][e] = 0.f;

    for (int kk = 0; kk < 64; ++kk) {
        const int k0 = nbase + kk * 32;
        gload16(&Ab[(size_t)srow * N_ + k0 + sq * 8],   &As[srow * 32 + sq * 8]);
        gload16(&Bb[(size_t)srow * 8192 + k0 + sq * 8], &Bs[srow * 32 + sq * 8]);
        __syncthreads();
        bf16x8 a[4], bb[2];
        #pragma unroll
        for (int mi = 0; mi < 4; ++mi)
            a[mi] = *(const bf16x8*)&As[(wc * 64 + mi * 16 + rl) * 32 + q * 8];
        #pragma unroll
        for (int ni = 0; ni < 2; ++ni)
            bb[ni] = *(const bf16x8*)&Bs[(wm * 32 + ni * 16 + rl) * 32 + q * 8];
        #pragma unroll
        for (int mi = 0; mi < 4; ++mi)
            #pragma unroll
            for (int ni = 0; ni < 2; ++ni)
                acc[mi][ni] = __builtin_amdgcn_mfma_f32_16x16x32_bf16(a[mi], bb[ni], acc[mi][ni], 0, 0, 0);
        __syncthreads();
    }

    float* ps = s ? p1 : p0;
    #pragma unroll
    for (int mi = 0; mi < 4; ++mi)
        #pragma unroll
        for (int ni = 0; ni < 2; ++ni)
            #pragma unroll
            for (int rr = 0; rr < 4; ++rr) {
                int c = tc * 128 + wc * 64 + mi * 16 + q * 4 + rr;
                int m = tm * 128 + wm * 32 + ni * 16 + rl;
                ps[((size_t)b * C_ + c) * N_ + m] = acc[mi][ni][rr];
            }
}

// out = gamma*(p0+p1) + x, vectorized
__global__ __launch_bounds__(256) void reduce_k(
    const float* __restrict__ p0, const float* __restrict__ p1,
    const float* __restrict__ x, const float* __restrict__ gamma,
    float* __restrict__ out)
{
    const float g = gamma[0];
    size_t i = (size_t)blockIdx.x * 256 + threadIdx.x;
    float4 a = ((const float4*)p0)[i];
    float4 b = ((const float4*)p1)[i];
    float4 xv = ((const float4*)x)[i];
    float4 o;
    o.x = (a.x + b.x) * g + xv.x;
    o.y = (a.y + b.y) * g + xv.y;
    o.z = (a.z + b.z) * g + xv.z;
    o.w = (a.w + b.w) * g + xv.w;
    ((float4*)out)[i] = o;
}

extern "C" void kernel_launch(void* const* d_in, const int* in_sizes, int n_in,
                              void* d_out, int out_size, void* d_ws, size_t ws_size,
                              hipStream_t stream) {
    const float* x     = (const float*)d_in[0];
    const float* ref_x = (const float*)d_in[1];
    const float* w1    = (const float*)d_in[2];
    const float* b1    = (const float*)d_in[3];
    const float* w2    = (const float*)d_in[4];
    const float* b2    = (const float*)d_in[5];
    const float* gamma = (const float*)d_in[6];
    float* out = (float*)d_out;

    char* ws = (char*)d_ws;
    size_t off = 0;
    auto nxt = [&](size_t bytes) {
        char* p = ws + off;
        off += (bytes + 255) & ~(size_t)255;
        return p;
    };
    unsigned short* f1x = (unsigned short*)nxt((size_t)B_ * N_ * C_ * 2);  // bf16 [b][m][c]
    unsigned short* f1r = (unsigned short*)nxt((size_t)B_ * N_ * C_ * 2);  // bf16 [b][n][c]
    unsigned short* f2  = (unsigned short*)nxt((size_t)B_ * N_ * C_ * 2);  // bf16 [b][c][n]
    unsigned short* xtx = (unsigned short*)nxt((size_t)B_ * N_ * C_ * 2);  // fp16 [b][p][c]
    unsigned short* xtr = (unsigned short*)nxt((size_t)B_ * N_ * C_ * 2);  // fp16 [b][p][c]
    unsigned short* w1h = (unsigned short*)nxt((size_t)9 * C_ * C_ * 2);   // fp16 [tap][o][i]
    unsigned short* w2h = (unsigned short*)nxt((size_t)9 * C_ * C_ * 2);   // fp16 [tap][o][i]
    float* corr = (float*)nxt((size_t)B_ * N_ * N_ * 4);                   // fp32 corrT [b][m][n]

    // split-K partials alias regions that are dead by the time gemm_out runs:
    // p0 over f1x+f1r (8MB, dead after gemm_corr), p1 over xtx+xtr (8MB, dead after convs)
    float* p0 = (float*)f1x;
    float* p1 = (float*)xtx;

    cvt_x_k<<<dim3(64, 4, B_), 256, 0, stream>>>(x, xtx);
    cvt_x_k<<<dim3(64, 4, B_), 256, 0, stream>>>(ref_x, xtr);
    cvt_w_k<<<2304, 256, 0, stream>>>(w1, w1h);
    cvt_w_k<<<2304, 256, 0, stream>>>(w2, w2h);

    conv_mfma_k<1><<<dim3(32, 4, B_), 256, 0, stream>>>(xtx, w1h, b1, f1x);
    conv_mfma_k<1><<<dim3(32, 4, B_), 256, 0, stream>>>(xtr, w1h, b1, f1r);
    conv_mfma_k<0><<<dim3(32, 4, B_), 256, 0, stream>>>(xtx, w2h, b2, f2);

    gemm_corr_k<<<dim3(32, 32, B_), 256, 0, stream>>>(f1x, f1r, corr);
    softmax_rows_k<<<dim3(N_, B_), 256, 0, stream>>>(corr);
    gemm_out_k<<<dim3(32, 4, B_), 512, 0, stream>>>(f2, corr, p0, p1);
    reduce_k<<<2048, 256, 0, stream>>>(p0, p1, x, gamma, out);
}

// Round 4
// 162.293 us; speedup vs baseline: 11.2700x; 1.3444x over previous
//
#include <hip/hip_runtime.h>
#include <hip/hip_bf16.h>

#define B_ 2
#define C_ 256
#define H_ 64
#define W_ 64
#define N_ 4096  // H_*W_

typedef short bf16x8 __attribute__((ext_vector_type(8)));
typedef _Float16 f16x8 __attribute__((ext_vector_type(8)));
typedef float f32x4 __attribute__((ext_vector_type(4)));

// float -> bf16 (round to nearest even), finite inputs
static __device__ __forceinline__ unsigned short f2bf(float f) {
    union { float f; unsigned u; } uf; uf.f = f;
    unsigned r = uf.u + 0x7fffu + ((uf.u >> 16) & 1u);
    return (unsigned short)(r >> 16);
}
// float -> fp16 bits
static __device__ __forceinline__ unsigned short f2h_u(float f) {
    union { _Float16 h; unsigned short u; } c; c.h = (_Float16)f; return c.u;
}

// async global->LDS, 16B per lane. LDS dest must be wave-uniform base + lane*16.
static __device__ __forceinline__ void gload16(const void* g, void* l) {
    __builtin_amdgcn_global_load_lds(
        (const __attribute__((address_space(1))) unsigned int*)g,
        (__attribute__((address_space(3))) unsigned int*)l, 16, 0, 0);
}

// ---------------------------------------------------------------------------
// Prep: [B][C][N] f32 -> [B][N][C] fp16, both inputs in one launch.
// z = which*2 + b
// ---------------------------------------------------------------------------
__global__ __launch_bounds__(256) void cvt_x_k(const float* __restrict__ x,
                                               const float* __restrict__ ref_x,
                                               unsigned short* __restrict__ xtx,
                                               unsigned short* __restrict__ xtr)
{
    __shared__ unsigned short t[64][72];
    const int pt = blockIdx.x, ct = blockIdx.y;
    const int which = blockIdx.z >> 1, b = blockIdx.z & 1;
    const float* in = which ? ref_x : x;
    unsigned short* out = which ? xtr : xtx;
    const int a = threadIdx.x & 63, r = threadIdx.x >> 6;
    #pragma unroll
    for (int i = 0; i < 16; ++i) {
        int c = i * 4 + r;
        t[c][a] = f2h_u(in[((size_t)(b * C_ + ct * 64 + c) << 12) + pt * 64 + a]);
    }
    __syncthreads();
    #pragma unroll
    for (int i = 0; i < 16; ++i) {
        int p = i * 4 + r;
        out[((size_t)(b * N_ + pt * 64 + p) << 8) + ct * 64 + a] = t[a][p];
    }
}

// Prep: both weights [O][I][3][3] f32 -> [tap][O][I] fp16 in one launch
__global__ __launch_bounds__(256) void cvt_w_k(const float* __restrict__ w1,
                                               const float* __restrict__ w2,
                                               unsigned short* __restrict__ wh1,
                                               unsigned short* __restrict__ wh2)
{
    int g = blockIdx.x;
    const float* w = (g < 2304) ? w1 : w2;
    unsigned short* wh = (g < 2304) ? wh1 : wh2;
    int i = (g % 2304) * 256 + threadIdx.x;         // < 9*256*256 exactly
    int ci = i & 255, co = (i >> 8) & 255, tap = i >> 16;
    wh[i] = f2h_u(w[((size_t)(co * 256 + ci)) * 9 + tap]);
}

// ---------------------------------------------------------------------------
// Implicit-GEMM 3x3 SAME conv + bias + relu via MFMA fp16 — all three convs
// fused into one launch: z = cid*2 + b, cid 0: conv1(x)->f1x [N][C],
// cid 1: conv1(ref_x)->f1r [N][C], cid 2: conv2(x)->f2 [C][N].
// Grid 768 blocks -> 2 blocks/CU resident (LDS 53.8KB), desynced barriers.
// ---------------------------------------------------------------------------
__global__ __launch_bounds__(256) void conv_mfma_k(
    const unsigned short* __restrict__ xtx, const unsigned short* __restrict__ xtr,
    const unsigned short* __restrict__ w1h, const unsigned short* __restrict__ w2h,
    const float* __restrict__ b1, const float* __restrict__ b2,
    unsigned short* __restrict__ f1x, unsigned short* __restrict__ f1r,
    unsigned short* __restrict__ f2)
{
    __shared__ unsigned short As[4 * 576 * 8];   // (q*576 + tap*64 + co)*8
    __shared__ unsigned short Bs[4 * 66 * 32];   // [row][col(pad)][ci-chunk swz]
    const int tid = threadIdx.x;
    const int pt  = blockIdx.x;   // 0..31 : plane rows pt*2, pt*2+1
    const int cot = blockIdx.y;   // 0..3
    const int cid = blockIdx.z >> 1;
    const int b   = blockIdx.z & 1;

    const unsigned short* xt = (cid == 1) ? xtr : xtx;
    const unsigned short* wt = (cid == 2) ? w2h : w1h;
    const float* bias = (cid == 2) ? b2 : b1;
    unsigned short* out = (cid == 0) ? f1x : (cid == 1) ? f1r : f2;
    const int trans = (cid != 2);

    const int lane = tid & 63, wid = tid >> 6;
    const int wco = wid >> 1, wpos = wid & 1;
    const int rl = lane & 15, q = lane >> 4;
    const int r0 = pt * 2;

    f32x4 acc[2][4];
    #pragma unroll
    for (int mi = 0; mi < 2; ++mi)
        #pragma unroll
        for (int ni = 0; ni < 4; ++ni)
            #pragma unroll
            for (int e = 0; e < 4; ++e) acc[mi][ni][e] = 0.f;

    for (int k0 = 0; k0 < C_; k0 += 32) {
        // stage A via global_load_lds: wave `wid` stages k-chunk q=wid, all taps
        #pragma unroll
        for (int tap = 0; tap < 9; ++tap) {
            gload16(wt + ((size_t)(tap * C_ + cot * 64 + lane) << 8) + k0 + wid * 8,
                    &As[(wid * 576 + tap * 64 + lane) * 8]);
        }
        // stage B: 4*66*4 = 1056 16B-chunks (zero-padded halo), swizzled
        #pragma unroll
        for (int j = 0; j < 5; ++j) {
            int it = tid + j * 256;
            if (it < 1056) {
                int col = it >> 4, sub = it & 15;
                int row = sub >> 2, qb = sub & 3;
                int h = r0 + row - 1, c = col - 1;
                float4 v; v.x = 0.f; v.y = 0.f; v.z = 0.f; v.w = 0.f;
                if (h >= 0 && h < 64 && c >= 0 && c < 64)
                    v = *(const float4*)(xt + ((size_t)(b * N_ + h * 64 + c) << 8) + k0 + qb * 8);
                int chunk = qb ^ ((col >> 1) & 3);
                *(float4*)&Bs[(row * 66 + col) * 32 + chunk * 8] = v;
            }
        }
        __syncthreads();

        #pragma unroll
        for (int tap = 0; tap < 9; ++tap) {
            const int kh = tap / 3, kw = tap % 3;
            f16x8 a0 = *(const f16x8*)&As[(q * 576 + tap * 64 + wco * 32 + rl) * 8];
            f16x8 a1 = *(const f16x8*)&As[(q * 576 + tap * 64 + wco * 32 + 16 + rl) * 8];
            const int chunkB = q ^ (((rl + kw) >> 1) & 3);
            const int rowB = (wpos + kh) * 66;
            #pragma unroll
            for (int ni = 0; ni < 4; ++ni) {
                int colB = ni * 16 + rl + kw;
                f16x8 bf = *(const f16x8*)&Bs[(rowB + colB) * 32 + chunkB * 8];
                acc[0][ni] = __builtin_amdgcn_mfma_f32_16x16x32_f16(a0, bf, acc[0][ni], 0, 0, 0);
                acc[1][ni] = __builtin_amdgcn_mfma_f32_16x16x32_f16(a1, bf, acc[1][ni], 0, 0, 0);
            }
        }
        __syncthreads();
    }

    // epilogue: C/D layout col=lane&15, row=(lane>>4)*4+rr
    #pragma unroll
    for (int mi = 0; mi < 2; ++mi) {
        const int co = cot * 64 + wco * 32 + mi * 16 + q * 4;
        float bs[4];
        #pragma unroll
        for (int rr = 0; rr < 4; ++rr) bs[rr] = bias[co + rr];
        #pragma unroll
        for (int ni = 0; ni < 4; ++ni) {
            const int pos = pt * 128 + wpos * 64 + ni * 16 + rl;
            if (trans) {
                unsigned short pk[4];
                #pragma unroll
                for (int rr = 0; rr < 4; ++rr)
                    pk[rr] = f2bf(fmaxf(acc[mi][ni][rr] + bs[rr], 0.f));
                uint2 u;
                u.x = (unsigned)pk[0] | ((unsigned)pk[1] << 16);
                u.y = (unsigned)pk[2] | ((unsigned)pk[3] << 16);
                *(uint2*)&out[((size_t)(b * N_ + pos) << 8) + co] = u;
            } else {
                #pragma unroll
                for (int rr = 0; rr < 4; ++rr)
                    out[((size_t)(b * C_ + co + rr) << 12) + pos] =
                        f2bf(fmaxf(acc[mi][ni][rr] + bs[rr], 0.f));
            }
        }
    }
}

// ---------------------------------------------------------------------------
// GEMM1 (m97 structure): corrT[b][m][n] = sum_c f1x[b][m][c]*f1r[b][n][c]
// 128x128 tile, 4 waves (2x2, each 64x64 = 4x4 frags), global_load_lds.
// ---------------------------------------------------------------------------
__global__ __launch_bounds__(256) void gemm_corr_k(
    const unsigned short* __restrict__ f1x, const unsigned short* __restrict__ f1r,
    float* __restrict__ corr)
{
    __shared__ alignas(16) unsigned short As[128 * 32];
    __shared__ alignas(16) unsigned short Bs[128 * 32];
    const int tid = threadIdx.x;
    const int tn = blockIdx.x, tm = blockIdx.y, b = blockIdx.z;

    const unsigned short* Ab = f1x + ((size_t)b * N_ + (size_t)tm * 128) * C_;
    const unsigned short* Bb = f1r + ((size_t)b * N_ + (size_t)tn * 128) * C_;

    const int wid = tid >> 6, lane = tid & 63;
    const int wr = wid >> 1, wc = wid & 1;
    const int rl = lane & 15, q = lane >> 4;
    const int srow = wid * 32 + (lane >> 2), sq = lane & 3;

    f32x4 acc[4][4];
    #pragma unroll
    for (int mi = 0; mi < 4; ++mi)
        #pragma unroll
        for (int ni = 0; ni < 4; ++ni)
            #pragma unroll
            for (int e = 0; e < 4; ++e) acc[mi][ni][e] = 0.f;

    for (int k0 = 0; k0 < C_; k0 += 32) {
        gload16(&Ab[(size_t)srow * C_ + k0 + sq * 8],        &As[srow * 32 + sq * 8]);
        gload16(&Ab[(size_t)(srow + 16) * C_ + k0 + sq * 8], &As[(srow + 16) * 32 + sq * 8]);
        gload16(&Bb[(size_t)srow * C_ + k0 + sq * 8],        &Bs[srow * 32 + sq * 8]);
        gload16(&Bb[(size_t)(srow + 16) * C_ + k0 + sq * 8], &Bs[(srow + 16) * 32 + sq * 8]);
        __syncthreads();
        bf16x8 a[4], bb[4];
        #pragma unroll
        for (int mi = 0; mi < 4; ++mi)
            a[mi] = *(const bf16x8*)&As[(wr * 64 + mi * 16 + rl) * 32 + q * 8];
        #pragma unroll
        for (int ni = 0; ni < 4; ++ni)
            bb[ni] = *(const bf16x8*)&Bs[(wc * 64 + ni * 16 + rl) * 32 + q * 8];
        #pragma unroll
        for (int mi = 0; mi < 4; ++mi)
            #pragma unroll
            for (int ni = 0; ni < 4; ++ni)
                acc[mi][ni] = __builtin_amdgcn_mfma_f32_16x16x32_bf16(a[mi], bb[ni], acc[mi][ni], 0, 0, 0);
        __syncthreads();
    }

    #pragma unroll
    for (int mi = 0; mi < 4; ++mi)
        #pragma unroll
        for (int ni = 0; ni < 4; ++ni)
            #pragma unroll
            for (int rr = 0; rr < 4; ++rr) {
                int m = tm * 128 + wr * 64 + mi * 16 + q * 4 + rr;
                int n = tn * 128 + wc * 64 + ni * 16 + rl;
                corr[((size_t)b * N_ + m) * N_ + n] = acc[mi][ni][rr];
            }
}

// ---------------------------------------------------------------------------
// Row softmax over corrT rows; reads fp32, writes bf16 packed into the
// FRONT half of the same row (in-place, block owns its row).
// ---------------------------------------------------------------------------
__global__ __launch_bounds__(256) void softmax_rows_k(float* __restrict__ corr)
{
    __shared__ float red[4];
    const int m = blockIdx.x, b = blockIdx.y;
    float* row = corr + ((size_t)b * N_ + m) * N_;
    float4* row4 = (float4*)row;
    const int tid = threadIdx.x;
    const int wid = tid >> 6, lane = tid & 63;

    float4 v[4];
    float mx = -3.0e38f;
    #pragma unroll
    for (int j = 0; j < 4; ++j) {
        v[j] = row4[tid + j * 256];
        mx = fmaxf(mx, fmaxf(fmaxf(v[j].x, v[j].y), fmaxf(v[j].z, v[j].w)));
    }
    #pragma unroll
    for (int off = 32; off; off >>= 1) mx = fmaxf(mx, __shfl_xor(mx, off));
    if (lane == 0) red[wid] = mx;
    __syncthreads();
    mx = fmaxf(fmaxf(red[0], red[1]), fmaxf(red[2], red[3]));
    __syncthreads();

    float s = 0.f;
    #pragma unroll
    for (int j = 0; j < 4; ++j) {
        v[j].x = __expf(v[j].x - mx);
        v[j].y = __expf(v[j].y - mx);
        v[j].z = __expf(v[j].z - mx);
        v[j].w = __expf(v[j].w - mx);
        s += v[j].x + v[j].y + v[j].z + v[j].w;
    }
    #pragma unroll
    for (int off = 32; off; off >>= 1) s += __shfl_xor(s, off);
    if (lane == 0) red[wid] = s;
    __syncthreads();
    s = red[0] + red[1] + red[2] + red[3];
    const float inv = 1.f / s;

    unsigned short* rb = (unsigned short*)row;
    #pragma unroll
    for (int j = 0; j < 4; ++j) {
        uint2 u;
        u.x = (unsigned)f2bf(v[j].x * inv) | ((unsigned)f2bf(v[j].y * inv) << 16);
        u.y = (unsigned)f2bf(v[j].z * inv) | ((unsigned)f2bf(v[j].w * inv) << 16);
        *(uint2*)&rb[4 * (tid + j * 256)] = u;
    }
}

// ---------------------------------------------------------------------------
// GEMM2 split-K=4: partial[s][b][c][m] = sum_{n in s-range} f2[b][c][n]*P[m][n]
// Tile 128c x 128m, 8 waves (2c x 4m). blockIdx.y = tc*4 + s. Grid 512 blocks.
// P read as bf16 (front half of fp32 corr rows, row stride 8192 ushorts).
// Partials live in the DEAD BACK HALVES of corr rows: element e maps to
// corr[(e>>11)*4096 + 2048 + (e&2047)] — byte-disjoint from P fronts.
// ---------------------------------------------------------------------------
__global__ __launch_bounds__(512) void gemm_out_k(
    const unsigned short* __restrict__ f2, float* __restrict__ corr)
{
    __shared__ alignas(16) unsigned short As[128 * 32];
    __shared__ alignas(16) unsigned short Bs[128 * 32];
    const int tid = threadIdx.x;
    const int tm = blockIdx.x;                 // 0..31
    const int tc = blockIdx.y >> 2;            // 0..1
    const int s  = blockIdx.y & 3;             // split 0..3
    const int b  = blockIdx.z;

    const unsigned short* Ab = f2 + ((size_t)b * C_ + (size_t)tc * 128) * N_;
    const unsigned short* Bb = (const unsigned short*)corr
                             + ((size_t)b * N_ + (size_t)tm * 128) * 8192;

    const int wid = tid >> 6, lane = tid & 63;
    const int wc = wid >> 2, wm = wid & 3;
    const int rl = lane & 15, q = lane >> 4;
    const int srow = wid * 16 + (lane >> 2), sq = lane & 3;
    const int nbase = s * 1024;

    f32x4 acc[4][2];
    #pragma unroll
    for (int mi = 0; mi < 4; ++mi)
        #pragma unroll
        for (int ni = 0; ni < 2; ++ni)
            #pragma unroll
            for (int e = 0; e < 4; ++e) acc[mi][ni][e] = 0.f;

    for (int kk = 0; kk < 32; ++kk) {
        const int k0 = nbase + kk * 32;
        gload16(&Ab[(size_t)srow * N_ + k0 + sq * 8],   &As[srow * 32 + sq * 8]);
        gload16(&Bb[(size_t)srow * 8192 + k0 + sq * 8], &Bs[srow * 32 + sq * 8]);
        __syncthreads();
        bf16x8 a[4], bb[2];
        #pragma unroll
        for (int mi = 0; mi < 4; ++mi)
            a[mi] = *(const bf16x8*)&As[(wc * 64 + mi * 16 + rl) * 32 + q * 8];
        #pragma unroll
        for (int ni = 0; ni < 2; ++ni)
            bb[ni] = *(const bf16x8*)&Bs[(wm * 32 + ni * 16 + rl) * 32 + q * 8];
        #pragma unroll
        for (int mi = 0; mi < 4; ++mi)
            #pragma unroll
            for (int ni = 0; ni < 2; ++ni)
                acc[mi][ni] = __builtin_amdgcn_mfma_f32_16x16x32_bf16(a[mi], bb[ni], acc[mi][ni], 0, 0, 0);
        __syncthreads();
    }

    #pragma unroll
    for (int mi = 0; mi < 4; ++mi)
        #pragma unroll
        for (int ni = 0; ni < 2; ++ni)
            #pragma unroll
            for (int rr = 0; rr < 4; ++rr) {
                int c = tc * 128 + wc * 64 + mi * 16 + q * 4 + rr;
                int m = tm * 128 + wm * 32 + ni * 16 + rl;
                size_t e = (((size_t)(s * 2 + b) * C_ + c) << 12) + m;
                corr[(e >> 11) * 4096 + 2048 + (e & 2047)] = acc[mi][ni][rr];
            }
}

// out = gamma*(p0+p1+p2+p3) + x ; partials read back from corr back-halves
__global__ __launch_bounds__(256) void reduce_k(
    const float* __restrict__ corr, const float* __restrict__ x,
    const float* __restrict__ gamma, float* __restrict__ out)
{
    const float g = gamma[0];
    size_t i = (size_t)blockIdx.x * 256 + threadIdx.x;   // float4 index
    size_t idx = i << 2;                                  // flat f32 index (b,c,m)
    float4 sum; sum.x = 0.f; sum.y = 0.f; sum.z = 0.f; sum.w = 0.f;
    #pragma unroll
    for (int sp = 0; sp < 4; ++sp) {
        size_t e = (size_t)sp * 2097152 + idx;
        float4 v = *(const float4*)&corr[(e >> 11) * 4096 + 2048 + (e & 2047)];
        sum.x += v.x; sum.y += v.y; sum.z += v.z; sum.w += v.w;
    }
    float4 xv = ((const float4*)x)[i];
    float4 o;
    o.x = sum.x * g + xv.x;
    o.y = sum.y * g + xv.y;
    o.z = sum.z * g + xv.z;
    o.w = sum.w * g + xv.w;
    ((float4*)out)[i] = o;
}

extern "C" void kernel_launch(void* const* d_in, const int* in_sizes, int n_in,
                              void* d_out, int out_size, void* d_ws, size_t ws_size,
                              hipStream_t stream) {
    const float* x     = (const float*)d_in[0];
    const float* ref_x = (const float*)d_in[1];
    const float* w1    = (const float*)d_in[2];
    const float* b1    = (const float*)d_in[3];
    const float* w2    = (const float*)d_in[4];
    const float* b2    = (const float*)d_in[5];
    const float* gamma = (const float*)d_in[6];
    float* out = (float*)d_out;

    char* ws = (char*)d_ws;
    size_t off = 0;
    auto nxt = [&](size_t bytes) {
        char* p = ws + off;
        off += (bytes + 255) & ~(size_t)255;
        return p;
    };
    unsigned short* f1x = (unsigned short*)nxt((size_t)B_ * N_ * C_ * 2);  // bf16 [b][m][c]
    unsigned short* f1r = (unsigned short*)nxt((size_t)B_ * N_ * C_ * 2);  // bf16 [b][n][c]
    unsigned short* f2  = (unsigned short*)nxt((size_t)B_ * N_ * C_ * 2);  // bf16 [b][c][n]
    unsigned short* xtx = (unsigned short*)nxt((size_t)B_ * N_ * C_ * 2);  // fp16 [b][p][c]
    unsigned short* xtr = (unsigned short*)nxt((size_t)B_ * N_ * C_ * 2);  // fp16 [b][p][c]
    unsigned short* w1h = (unsigned short*)nxt((size_t)9 * C_ * C_ * 2);   // fp16 [tap][o][i]
    unsigned short* w2h = (unsigned short*)nxt((size_t)9 * C_ * C_ * 2);   // fp16 [tap][o][i]
    float* corr = (float*)nxt((size_t)B_ * N_ * N_ * 4);                   // fp32 corrT [b][m][n]

    cvt_x_k<<<dim3(64, 4, 4), 256, 0, stream>>>(x, ref_x, xtx, xtr);
    cvt_w_k<<<4608, 256, 0, stream>>>(w1, w2, w1h, w2h);

    conv_mfma_k<<<dim3(32, 4, 6), 256, 0, stream>>>(xtx, xtr, w1h, w2h, b1, b2,
                                                    f1x, f1r, f2);

    gemm_corr_k<<<dim3(32, 32, B_), 256, 0, stream>>>(f1x, f1r, corr);
    softmax_rows_k<<<dim3(N_, B_), 256, 0, stream>>>(corr);
    gemm_out_k<<<dim3(32, 8, B_), 512, 0, stream>>>(f2, corr);
    reduce_k<<<2048, 256, 0, stream>>>(corr, x, gamma, out);
}